// Round 14
// baseline (1099.712 us; speedup 1.0000x reference)
//
#include <hip/hip_runtime.h>
#include <math.h>

#define NN 20000
#define LL 64
#define EE 320000
#define DD 128
#define KK 20
#define NLAYER 4
#define TOUT 45  // LL - KK + 1

#define EPS_BN 1e-5f
#define EPS_AGG 1e-6f

#define SEQ_KP 96   // one-hot K (80) padded to 3 MFMA k-steps
#define SEQ_AP 104  // A-tile row stride (f16): 16B-aligned, 2-way-conflict only

#define ESLOTS 32   // edge-BN stat slots; round-14: per-wave direct atomics
                    // (4 waves x 2500 blocks / 32 slots ~ 312 per address,
                    // under the round-12-proven contention regime)

// Wave-local LDS sync: what __syncthreads lowers to for a 1-wave block,
// minus s_barrier. Required between same-wave ds_write -> ds_read.
#define WAVE_LDS_FENCE() __asm__ volatile("s_waitcnt lgkmcnt(0)" ::: "memory")

typedef unsigned short u16;
typedef __attribute__((ext_vector_type(8))) short short8;      // 8 bf16
typedef __attribute__((ext_vector_type(8))) unsigned short ushort8;
typedef __attribute__((ext_vector_type(8))) _Float16 half8;    // 8 f16
typedef __attribute__((ext_vector_type(4))) float floatx4;     // MFMA C/D

// bf16 <-> fp32 (RNE).
__device__ __forceinline__ float b2f(u16 u) {
  union { unsigned int i; float f; } v;
  v.i = ((unsigned int)u) << 16;
  return v.f;
}
__device__ __forceinline__ u16 f2b(float f) {
  union { float f; unsigned int i; } v;
  v.f = f;
  unsigned int x = v.i;
  return (u16)((x + 0x7fffu + ((x >> 16) & 1u)) >> 16);
}

// ---------------------------------------------------------------------------
__global__ void zero_i32(int* __restrict__ p, int n)
{
  int i = blockIdx.x * 256 + threadIdx.x;
  if (i < n) p[i] = 0;
}

__global__ void diag_k(float* __restrict__ out, float v) { out[0] = v; }

// One kernel casts all 5 weight stacks to bf16 (5 * NLAYER*DD*DD elements).
__global__ void cast_weights(
    const float* __restrict__ Cw, const float* __restrict__ Aw,
    const float* __restrict__ Bw, const float* __restrict__ Dw,
    const float* __restrict__ Ew, u16* __restrict__ Cwb, u16* __restrict__ Anb,
    u16* __restrict__ Bnb, u16* __restrict__ Dnb, u16* __restrict__ Enb)
{
  int idx = blockIdx.x * 256 + threadIdx.x;  // exact 5*65536
  int which = idx >> 16, off = idx & 65535;
  const float* s;
  u16* d;
  switch (which) {
    case 0: s = Cw; d = Cwb; break;
    case 1: s = Aw; d = Anb; break;
    case 2: s = Bw; d = Bnb; break;
    case 3: s = Dw; d = Dnb; break;
    default: s = Ew; d = Enb; break;
  }
  d[off] = f2b(s[off]);
}

// ---------------------------------------------------------------------------
// WS[(k,s)][d] = sum_j emb[s][j] * conv_w[d][j][k], fp32 math, stored f16.
// ---------------------------------------------------------------------------
__global__ void build_ws(const float* __restrict__ emb,
                         const float* __restrict__ conv_w,
                         _Float16* __restrict__ WSf)
{
  int idx = blockIdx.x * 256 + threadIdx.x;
  if (idx >= DD * SEQ_KP) return;
  int d = idx / SEQ_KP;
  int c = idx - d * SEQ_KP;
  float v = 0.f;
  if (c < 80) {
    int k = c >> 2, s = c & 3;
    v = emb[s * 3 + 0] * conv_w[d * 60 + k] +
        emb[s * 3 + 1] * conv_w[d * 60 + 20 + k] +
        emb[s * 3 + 2] * conv_w[d * 60 + 40 + k];
  }
  WSf[idx] = (_Float16)v;
}

// ---------------------------------------------------------------------------
// Sequence encoder via f16 MFMA on an EXACT one-hot im2col (round-6 proven).
// ---------------------------------------------------------------------------
__global__ __launch_bounds__(256) void seq_encoder(
    const _Float16* __restrict__ WSf, const float* __restrict__ conv_b,
    const int* __restrict__ reads, float* __restrict__ h,
    u16* __restrict__ h_bf)
{
  __shared__ int rd[LL];
  __shared__ _Float16 As[48][SEQ_AP];
  int tid = threadIdx.x;
  int n = blockIdx.x;
  if (tid < LL) rd[tid] = reads[n * LL + tid];
  __syncthreads();

#pragma unroll
  for (int it = 0; it < 20; it++) {
    int idx = tid + it * 256;  // covers 48*104 = 4992
    if (idx < 48 * SEQ_AP) {
      int t = idx / SEQ_AP;
      int c = idx - t * SEQ_AP;
      _Float16 v = (_Float16)0.f;
      if (t < TOUT && c < 80) {
        int k = c >> 2, s = c & 3;
        v = (rd[t + k] == s) ? (_Float16)1.f : (_Float16)0.f;
      }
      (&As[0][0])[idx] = v;
    }
  }
  __syncthreads();

  int lane = tid & 63;
  int wv = tid >> 6;
  int m = lane & 15;
  int q = lane >> 4;

  half8 a[3][3];
#pragma unroll
  for (int mt = 0; mt < 3; mt++)
#pragma unroll
    for (int ks = 0; ks < 3; ks++)
      a[mt][ks] = *(const half8*)&As[mt * 16 + m][ks * 32 + q * 8];

  floatx4 acc[3][2];
#pragma unroll
  for (int mt = 0; mt < 3; mt++)
#pragma unroll
    for (int nt = 0; nt < 2; nt++) acc[mt][nt] = (floatx4){0.f, 0.f, 0.f, 0.f};

#pragma unroll
  for (int ks = 0; ks < 3; ks++) {
#pragma unroll
    for (int nt = 0; nt < 2; nt++) {
      int row = (wv * 2 + nt) * 16 + m;  // output channel
      half8 b = *(const half8*)(WSf + (size_t)row * SEQ_KP + ks * 32 + q * 8);
#pragma unroll
      for (int mt = 0; mt < 3; mt++)
        acc[mt][nt] = __builtin_amdgcn_mfma_f32_16x16x32_f16(a[mt][ks], b,
                                                             acc[mt][nt], 0, 0, 0);
    }
  }

#pragma unroll
  for (int nt = 0; nt < 2; nt++) {
    float mx = -1e30f;
#pragma unroll
    for (int mt = 0; mt < 3; mt++) {
#pragma unroll
      for (int r = 0; r < 4; r++) {
        int row = mt * 16 + q * 4 + r;
        float v = acc[mt][nt][r];
        mx = (row < TOUT) ? fmaxf(mx, v) : mx;
      }
    }
    mx = fmaxf(mx, __shfl_xor(mx, 16, 64));
    mx = fmaxf(mx, __shfl_xor(mx, 32, 64));
    if (lane < 16) {
      int col = (wv * 2 + nt) * 16 + lane;
      float hv = fmaxf(mx + conv_b[col], 0.f);
      h[n * DD + col] = hv;
      h_bf[n * DD + col] = f2b(hv);
    }
  }
}

// ---------------------------------------------------------------------------
// Edge encoder, CSR-permuted slots, 8 channels (16B store) per thread.
// ---------------------------------------------------------------------------
__global__ __launch_bounds__(256) void edge_encoder(
    const float* __restrict__ sim, const float* __restrict__ len,
    const float* __restrict__ ee_w, const float* __restrict__ ee_b,
    const int* __restrict__ ceid, u16* __restrict__ e)
{
  int idx = blockIdx.x * 256 + threadIdx.x;  // EE*DD/8 exactly
  int p = idx >> 4;
  int c0 = (idx & 15) * 8;
  int eid = ceid[p];
  float sv = sim[eid], lv = len[eid];
  ushort8 o;
#pragma unroll
  for (int j = 0; j < 8; j++) {
    int c = c0 + j;
    o[j] = f2b(fmaf(sv, ee_w[2 * c], fmaf(lv, ee_w[2 * c + 1], ee_b[c])));
  }
  *(ushort8*)&e[(size_t)p * DD + c0] = o;
}

// ---------------------------------------------------------------------------
// CSR build (by dst): histogram -> 1-block scan -> scatter -> permuted arrays
// ---------------------------------------------------------------------------
__global__ void hist_kernel(const int* __restrict__ dst, int* __restrict__ deg)
{
  int i = blockIdx.x * 256 + threadIdx.x;
  if (i < EE) atomicAdd(&deg[dst[i]], 1);
}

__global__ __launch_bounds__(1024) void scan_kernel(
    const int* __restrict__ deg, int* __restrict__ off, int* __restrict__ cur)
{
  __shared__ int ss[1024];
  const int CH = 20;
  int tid = threadIdx.x;
  int base = tid * CH;
  int s = 0;
  for (int j = 0; j < CH; j++) {
    int i = base + j;
    if (i < NN) s += deg[i];
  }
  ss[tid] = s;
  __syncthreads();
  for (int o = 1; o < 1024; o <<= 1) {
    int v = (tid >= o) ? ss[tid - o] : 0;
    __syncthreads();
    ss[tid] += v;
    __syncthreads();
  }
  int run = (tid == 0) ? 0 : ss[tid - 1];
  for (int j = 0; j < CH; j++) {
    int i = base + j;
    if (i < NN) {
      off[i] = run;
      cur[i] = run;
      run += deg[i];
    }
  }
  if (base <= NN && NN < base + CH) off[NN] = run;
}

__global__ void scatter_kernel(const int* __restrict__ dst, int* __restrict__ cur,
                               int* __restrict__ csr)
{
  int i = blockIdx.x * 256 + threadIdx.x;
  if (i < EE) {
    int p = atomicAdd(&cur[dst[i]], 1);
    csr[p] = i;
  }
}

__global__ void build_perm(const int* __restrict__ ceid,
                           const int* __restrict__ src,
                           const int* __restrict__ dst,
                           int* __restrict__ sp, int* __restrict__ dp)
{
  int i = blockIdx.x * 256 + threadIdx.x;
  if (i < EE) {
    int eid = ceid[i];
    sp[i] = src[eid];
    dp[i] = dst[eid];
  }
}

// ---------------------------------------------------------------------------
// Node projections via bf16 MFMA + LDS-transposed coalesced ushort8 stores.
// Gs stride 128 (16B-aligned rows, LDS exactly 32 KB -> 5 blocks/CU).
// Intra-wave syncs are WAVE_LDS_FENCE (wave-private Gs tile). Block (0,0)
// zeroes the BN-stats region.
// ---------------------------------------------------------------------------
__global__ __launch_bounds__(256) void gemm_node_mfma(
    const u16* __restrict__ hbf,
    const u16* __restrict__ W0, const u16* __restrict__ W1,
    const u16* __restrict__ W2, const u16* __restrict__ W3,
    const float* __restrict__ b0, const float* __restrict__ b1,
    const float* __restrict__ b2, const float* __restrict__ b3,
    u16* __restrict__ O0, u16* __restrict__ O1,
    u16* __restrict__ O2, u16* __restrict__ O3,
    float* __restrict__ stats)
{
  __shared__ float Gs[4][16][128];
  if (blockIdx.x == 0 && blockIdx.y == 0) {
    const int nstat = 2 * ESLOTS * DD + 2 * 64 * DD;
    for (int j = threadIdx.x; j < nstat; j += 256) stats[j] = 0.f;
  }
  const u16* W;
  const float* bias;
  u16* O;
  switch (blockIdx.y) {
    case 0: W = W0; bias = b0; O = O0; break;
    case 1: W = W1; bias = b1; O = O1; break;
    case 2: W = W2; bias = b2; O = O2; break;
    default: W = W3; bias = b3; O = O3; break;
  }
  int lane = threadIdx.x & 63;
  int wv = threadIdx.x >> 6;
  int rbase = blockIdx.x * 128 + wv * 32;
  int m = lane & 15;
  int q = lane >> 4;

  floatx4 acc[2][8];
#pragma unroll
  for (int rt = 0; rt < 2; rt++)
#pragma unroll
    for (int ct = 0; ct < 8; ct++) acc[rt][ct] = (floatx4){0.f, 0.f, 0.f, 0.f};

  int r0 = rbase + m;
  int r0c = r0 < NN ? r0 : NN - 1;
  int r1c = (r0 + 16) < NN ? (r0 + 16) : NN - 1;
  size_t a0base = (size_t)r0c * DD + q * 8;
  size_t a1base = (size_t)r1c * DD + q * 8;
  size_t bbase = (size_t)m * DD + q * 8;

#pragma unroll
  for (int ks = 0; ks < 4; ks++) {
    short8 a0 = *(const short8*)(hbf + a0base + ks * 32);
    short8 a1 = *(const short8*)(hbf + a1base + ks * 32);
#pragma unroll
    for (int ct = 0; ct < 8; ct++) {
      short8 b = *(const short8*)(W + bbase + (size_t)ct * 16 * DD + ks * 32);
      acc[0][ct] = __builtin_amdgcn_mfma_f32_16x16x32_bf16(a0, b, acc[0][ct], 0, 0, 0);
      acc[1][ct] = __builtin_amdgcn_mfma_f32_16x16x32_bf16(a1, b, acc[1][ct], 0, 0, 0);
    }
  }

  float cb[8];
#pragma unroll
  for (int ct = 0; ct < 8; ct++) cb[ct] = bias[ct * 16 + m];

  int rg = lane >> 4, cg = lane & 15;
#pragma unroll
  for (int rt = 0; rt < 2; rt++) {
#pragma unroll
    for (int ct = 0; ct < 8; ct++)
#pragma unroll
      for (int r = 0; r < 4; r++)
        Gs[wv][q * 4 + r][ct * 16 + m] = acc[rt][ct][r] + cb[ct];
    WAVE_LDS_FENCE();  // writes committed before same-wave reads
#pragma unroll
    for (int k = 0; k < 4; k++) {
      int ri = k * 4 + rg;
      int grow = rbase + rt * 16 + ri;
      if (grow < NN) {
        ushort8 ov;
#pragma unroll
        for (int j = 0; j < 8; j++) ov[j] = f2b(Gs[wv][ri][cg * 8 + j]);
        *(ushort8*)(O + (size_t)grow * DD + cg * 8) = ov;
      }
    }
    WAVE_LDS_FENCE();  // reads done before next rt overwrites the tile
  }
}

// ---------------------------------------------------------------------------
// E1: edge GEMM (bf16 MFMA) + LDS-transposed epilogue + fused BN stats.
// Round-14: Gs stride 128 (LDS exactly 32 KB -> 5 blocks/CU, was 37.9 KB/4);
// cross-wave stats LDS + final __syncthreads deleted — each wave atomicAdds
// its own partials to slot (blockIdx*4+wv)&31.
// ---------------------------------------------------------------------------
__global__ __launch_bounds__(256) void gemm_edge_mfma(
    const u16* __restrict__ e, const u16* __restrict__ Cwb,
    const float* __restrict__ Cb, const u16* __restrict__ Dh,
    const u16* __restrict__ Eh, const int* __restrict__ sp,
    const int* __restrict__ dp, u16* __restrict__ ehat,
    float* __restrict__ p1e, float* __restrict__ p2e)
{
  __shared__ float Gs[4][16][128];
  int lane = threadIdx.x & 63;
  int wv = threadIdx.x >> 6;
  int rbase = blockIdx.x * 128 + wv * 32;
  int m = lane & 15;
  int q = lane >> 4;
  int rg = q, cg = m;
  int c0 = cg * 8;

  // Prefetch epilogue gather indices (independent of the GEMM).
  int dnv[8], snv[8];
#pragma unroll
  for (int rt = 0; rt < 2; rt++)
#pragma unroll
    for (int k = 0; k < 4; k++) {
      int grow = rbase + rt * 16 + k * 4 + rg;
      dnv[rt * 4 + k] = dp[grow];
      snv[rt * 4 + k] = sp[grow];
    }

  floatx4 acc[2][8];
#pragma unroll
  for (int rt = 0; rt < 2; rt++)
#pragma unroll
    for (int ct = 0; ct < 8; ct++) acc[rt][ct] = (floatx4){0.f, 0.f, 0.f, 0.f};

  size_t abase = (size_t)(rbase + m) * DD + q * 8;
  size_t bbase = (size_t)m * DD + q * 8;

#pragma unroll
  for (int ks = 0; ks < 4; ks++) {
    short8 a0 = *(const short8*)(e + abase + ks * 32);
    short8 a1 = *(const short8*)(e + abase + 16 * DD + ks * 32);
#pragma unroll
    for (int ct = 0; ct < 8; ct++) {
      short8 b = *(const short8*)(Cwb + bbase + (size_t)ct * 16 * DD + ks * 32);
      acc[0][ct] = __builtin_amdgcn_mfma_f32_16x16x32_bf16(a0, b, acc[0][ct], 0, 0, 0);
      acc[1][ct] = __builtin_amdgcn_mfma_f32_16x16x32_bf16(a1, b, acc[1][ct], 0, 0, 0);
    }
  }

  float cb[8];
#pragma unroll
  for (int ct = 0; ct < 8; ct++) cb[ct] = Cb[ct * 16 + m];

  float s1[8], s2[8];
#pragma unroll
  for (int j = 0; j < 8; j++) { s1[j] = 0.f; s2[j] = 0.f; }

#pragma unroll
  for (int rt = 0; rt < 2; rt++) {
#pragma unroll
    for (int ct = 0; ct < 8; ct++)
#pragma unroll
      for (int r = 0; r < 4; r++)
        Gs[wv][q * 4 + r][ct * 16 + m] = acc[rt][ct][r] + cb[ct];
    WAVE_LDS_FENCE();
#pragma unroll
    for (int k = 0; k < 4; k++) {
      int ri = k * 4 + rg;
      int grow = rbase + rt * 16 + ri;
      int dn = dnv[rt * 4 + k], sn = snv[rt * 4 + k];
      ushort8 dh = *(const ushort8*)(Dh + (size_t)dn * DD + c0);
      ushort8 eh = *(const ushort8*)(Eh + (size_t)sn * DD + c0);
      ushort8 ov;
#pragma unroll
      for (int j = 0; j < 8; j++) {
        float v = Gs[wv][ri][c0 + j] + b2f(dh[j]) + b2f(eh[j]);
        ov[j] = f2b(v);
        s1[j] += v;
        s2[j] = fmaf(v, v, s2[j]);
      }
      *(ushort8*)(ehat + (size_t)grow * DD + c0) = ov;
    }
    WAVE_LDS_FENCE();
  }

  // Per-wave stats: reduce across the 4 row-groups, then direct atomics.
  int slot = ((blockIdx.x * 4 + wv) & (ESLOTS - 1)) * DD;
#pragma unroll
  for (int j = 0; j < 8; j++) {
    float a1 = s1[j], a2 = s2[j];
    a1 += __shfl_down(a1, 16, 64);
    a1 += __shfl_down(a1, 32, 64);
    a2 += __shfl_down(a2, 16, 64);
    a2 += __shfl_down(a2, 32, 64);
    if (rg == 0) {
      atomicAdd(&p1e[slot + c0 + j], a1);
      atomicAdd(&p2e[slot + c0 + j], a2);
    }
  }
}

// ---------------------------------------------------------------------------
// E2: fused edge_update + aggregation. Two 32-lane halves per wave process
// different CSR rows (round-13 win). Round-14: BN-e finalize computed ONCE
// per block into LDS (was per-thread slot reduction — 8x less L2 traffic).
// ---------------------------------------------------------------------------
__global__ __launch_bounds__(256) void agg_fused(
    const u16* __restrict__ ehat, u16* __restrict__ e,
    const u16* __restrict__ Bh, const u16* __restrict__ Ah,
    const float* __restrict__ p1e, const float* __restrict__ p2e,
    const float* __restrict__ bng, const float* __restrict__ bnb,
    const int* __restrict__ coff, const int* __restrict__ sp,
    float* __restrict__ xb, float* __restrict__ p1n, float* __restrict__ p2n)
{
  __shared__ float xs[4][128];
  __shared__ float scs[128], shs[128];
  int tid = threadIdx.x;
  if (tid < 128) {
    int c = tid;
    float s1 = 0.f, s2 = 0.f;
    for (int k = 0; k < ESLOTS; k++) {
      s1 += p1e[k * DD + c];
      s2 += p2e[k * DD + c];
    }
    const float inv = 1.f / (float)EE;
    float mean = s1 * inv;
    float var = fmaxf(s2 * inv - mean * mean, 0.f);
    float sc = bng[c] * rsqrtf(var + EPS_BN);
    scs[c] = sc;
    shs[c] = fmaf(-mean, sc, bnb[c]);
  }
  __syncthreads();

  int wv = tid >> 6;
  int n = blockIdx.x * 4 + wv;  // NN = 20000 exact
  int lane = tid & 63;
  int half = lane >> 5;
  int sub = lane & 31;
  int c4 = sub * 4;

  float4 scv = *(const float4*)&scs[c4];
  float4 shv = *(const float4*)&shs[c4];
  float sc[4] = {scv.x, scv.y, scv.z, scv.w};
  float sh[4] = {shv.x, shv.y, shv.z, shv.w};

  int b = coff[n], en = coff[n + 1];
  float num[4] = {0.f, 0.f, 0.f, 0.f}, den[4] = {0.f, 0.f, 0.f, 0.f};
  for (int pb = b; pb < en; pb += 2) {
    int p = pb + half;
    if (p < en) {
      int sn = sp[p];
      ushort4 hv = *(const ushort4*)&ehat[(size_t)p * DD + c4];
      ushort4 ev = *(const ushort4*)&e[(size_t)p * DD + c4];
      ushort4 bh = *(const ushort4*)&Bh[(size_t)sn * DD + c4];
      u16 hvv[4] = {hv.x, hv.y, hv.z, hv.w};
      u16 evv[4] = {ev.x, ev.y, ev.z, ev.w};
      u16 bhv[4] = {bh.x, bh.y, bh.z, bh.w};
      u16 eo[4];
#pragma unroll
      for (int j = 0; j < 4; j++) {
        float v = b2f(hvv[j]);
        eo[j] = f2b(b2f(evv[j]) + fmaxf(fmaf(v, sc[j], sh[j]), 0.f));
        float s = 1.f / (1.f + __expf(-v));
        den[j] += s;
        num[j] = fmaf(s, b2f(bhv[j]), num[j]);
      }
      ushort4 eow = {eo[0], eo[1], eo[2], eo[3]};
      *(ushort4*)&e[(size_t)p * DD + c4] = eow;
    }
  }

#pragma unroll
  for (int j = 0; j < 4; j++) {
    num[j] += __shfl_down(num[j], 32, 64);
    den[j] += __shfl_down(den[j], 32, 64);
  }

  if (half == 0) {
    ushort4 av = *(const ushort4*)&Ah[(size_t)n * DD + c4];
    u16 avv[4] = {av.x, av.y, av.z, av.w};
    float x[4];
#pragma unroll
    for (int j = 0; j < 4; j++)
      x[j] = b2f(avv[j]) + num[j] / (den[j] + EPS_AGG);
    *(float4*)&xb[(size_t)n * DD + c4] = make_float4(x[0], x[1], x[2], x[3]);
#pragma unroll
    for (int j = 0; j < 4; j++) xs[wv][c4 + j] = x[j];
  }
  __syncthreads();
  if (threadIdx.x < 128) {
    int c = threadIdx.x;
    float a0 = xs[0][c], a1 = xs[1][c], a2 = xs[2][c], a3 = xs[3][c];
    float s1v = (a0 + a1) + (a2 + a3);
    float s2v = fmaf(a0, a0, fmaf(a1, a1, fmaf(a2, a2, a3 * a3)));
    int slot = blockIdx.x & 63;
    atomicAdd(&p1n[slot * DD + c], s1v);
    atomicAdd(&p2n[slot * DD + c], s2v);
  }
}

// ---------------------------------------------------------------------------
// Node update: scale/shift computed once per block into LDS, then
// float4/ushort4 grid-stride streaming.
// ---------------------------------------------------------------------------
__global__ __launch_bounds__(256) void node_update(
    const float* __restrict__ x, const float* __restrict__ p1n,
    const float* __restrict__ p2n, const float* __restrict__ g,
    const float* __restrict__ b, float* __restrict__ h,
    u16* __restrict__ h_bf)
{
  __shared__ float scs[128], shs[128];
  int tid = threadIdx.x;
  if (tid < 128) {
    int c = tid;
    float s1 = 0.f, s2 = 0.f;
    for (int k = 0; k < 64; k++) {
      s1 += p1n[k * DD + c];
      s2 += p2n[k * DD + c];
    }
    const float inv = 1.f / (float)NN;
    float mean = s1 * inv;
    float var = fmaxf(s2 * inv - mean * mean, 0.f);
    float sc = g[c] * rsqrtf(var + EPS_BN);
    scs[c] = sc;
    shs[c] = fmaf(-mean, sc, b[c]);
  }
  __syncthreads();
  for (int i = blockIdx.x * 256 + tid; i < NN * DD / 4; i += 256 * 256) {
    int base = i * 4;
    int c0 = base & 127;
    float4 xv = *(const float4*)&x[base];
    float4 hv = *(const float4*)&h[base];
    float4 sc = *(const float4*)&scs[c0];
    float4 shv = *(const float4*)&shs[c0];
    float4 ho;
    ho.x = hv.x + fmaxf(fmaf(xv.x, sc.x, shv.x), 0.f);
    ho.y = hv.y + fmaxf(fmaf(xv.y, sc.y, shv.y), 0.f);
    ho.z = hv.z + fmaxf(fmaf(xv.z, sc.z, shv.z), 0.f);
    ho.w = hv.w + fmaxf(fmaf(xv.w, sc.w, shv.w), 0.f);
    *(float4*)&h[base] = ho;
    ushort4 hb = {f2b(ho.x), f2b(ho.y), f2b(ho.z), f2b(ho.w)};
    *(ushort4*)&h_bf[base] = hb;
  }
}

// ---------------------------------------------------------------------------
// Decoder: one wave per CSR position p; scatter-store to out[ceid[p]].
// ---------------------------------------------------------------------------
__global__ __launch_bounds__(256) void decoder_k(
    const float* __restrict__ h, const u16* __restrict__ e,
    const int* __restrict__ ceid, const int* __restrict__ sp,
    const int* __restrict__ dp, const float* __restrict__ dw,
    const float* __restrict__ db, float* __restrict__ out)
{
  int p = (blockIdx.x * 256 + threadIdx.x) >> 6;  // < EE exactly
  int lane = threadIdx.x & 63;
  int s = sp[p], dd = dp[p];
  float acc = 0.f;
#pragma unroll
  for (int half = 0; half < 2; half++) {
    int c = lane + half * 64;
    acc = fmaf(dw[c], h[(size_t)s * DD + c], acc);
    acc = fmaf(dw[DD + c], h[(size_t)dd * DD + c], acc);
    acc = fmaf(dw[2 * DD + c], b2f(e[(size_t)p * DD + c]), acc);
  }
#pragma unroll
  for (int o = 32; o > 0; o >>= 1) acc += __shfl_down(acc, o, 64);
  if (lane == 0) out[ceid[p]] = acc + db[0];
}

// ---------------------------------------------------------------------------
extern "C" void kernel_launch(void* const* d_in, const int* in_sizes, int n_in,
                              void* d_out, int out_size, void* d_ws, size_t ws_size,
                              hipStream_t stream)
{
  const float* emb = (const float*)d_in[0];
  const float* conv_w = (const float*)d_in[1];
  const float* conv_b = (const float*)d_in[2];
  const float* ee_w = (const float*)d_in[3];
  const float* ee_b = (const float*)d_in[4];
  const float* Aw = (const float*)d_in[5];
  const float* Ab = (const float*)d_in[6];
  const float* Bw = (const float*)d_in[7];
  const float* Bb = (const float*)d_in[8];
  const float* Cw = (const float*)d_in[9];
  const float* Cb = (const float*)d_in[10];
  const float* Dw = (const float*)d_in[11];
  const float* Db = (const float*)d_in[12];
  const float* Ew = (const float*)d_in[13];
  const float* Eb = (const float*)d_in[14];
  const float* bnh_g = (const float*)d_in[15];
  const float* bnh_b = (const float*)d_in[16];
  const float* bne_g = (const float*)d_in[17];
  const float* bne_b = (const float*)d_in[18];
  const float* dec_w = (const float*)d_in[19];
  const float* dec_b = (const float*)d_in[20];
  const float* sim = (const float*)d_in[21];
  const float* leng = (const float*)d_in[22];
  const int* reads = (const int*)d_in[23];
  const int* src = (const int*)d_in[24];
  const int* dst = (const int*)d_in[25];
  float* out = (float*)d_out;

  char* ws = (char*)d_ws;
  size_t off = 0;
  auto alloc = [&](size_t b) -> void* {
    void* p = ws + off;
    off += (b + 255) & ~(size_t)255;
    return p;
  };
  float* h = (float*)alloc((size_t)NN * DD * 4);
  u16* h_bf = (u16*)alloc((size_t)NN * DD * 2);
  u16* e = (u16*)alloc((size_t)EE * DD * 2);       // CSR-permuted
  u16* ehat = (u16*)alloc((size_t)EE * DD * 2);    // CSR-permuted, raw e_hat
  u16* Ah = (u16*)alloc((size_t)NN * DD * 2);
  u16* Bh = (u16*)alloc((size_t)NN * DD * 2);
  u16* Dh = (u16*)alloc((size_t)NN * DD * 2);
  u16* Eh = (u16*)alloc((size_t)NN * DD * 2);
  float* xb = (float*)alloc((size_t)NN * DD * 4);
  float* stats = (float*)alloc((size_t)(2 * ESLOTS * DD + 2 * 64 * DD) * 4);
  float* p1e = stats;
  float* p2e = stats + ESLOTS * DD;
  float* p1n = stats + 2 * ESLOTS * DD;
  float* p2n = p1n + 64 * DD;
  u16* Cwb = (u16*)alloc((size_t)NLAYER * DD * DD * 2);
  u16* Anb = (u16*)alloc((size_t)NLAYER * DD * DD * 2);
  u16* Bnb = (u16*)alloc((size_t)NLAYER * DD * DD * 2);
  u16* Dnb = (u16*)alloc((size_t)NLAYER * DD * DD * 2);
  u16* Enb = (u16*)alloc((size_t)NLAYER * DD * DD * 2);
  _Float16* WSf = (_Float16*)alloc((size_t)DD * SEQ_KP * 2);
  int* deg = (int*)alloc((size_t)NN * 4);
  int* coff = (int*)alloc((size_t)(NN + 1) * 4);
  int* ccur = (int*)alloc((size_t)NN * 4);
  int* ceid = (int*)alloc((size_t)EE * 4);
  int* sp = (int*)alloc((size_t)EE * 4);
  int* dp = (int*)alloc((size_t)EE * 4);

  if (off > ws_size) {
    diag_k<<<1, 1, 0, stream>>>(out, (float)ws_size);
    return;
  }

  // CSR by dst + permuted index arrays (ws re-poisoned every call).
  zero_i32<<<(NN + 255) / 256, 256, 0, stream>>>(deg, NN);
  hist_kernel<<<(EE + 255) / 256, 256, 0, stream>>>(dst, deg);
  scan_kernel<<<1, 1024, 0, stream>>>(deg, coff, ccur);
  scatter_kernel<<<(EE + 255) / 256, 256, 0, stream>>>(dst, ccur, ceid);
  build_perm<<<(EE + 255) / 256, 256, 0, stream>>>(ceid, src, dst, sp, dp);

  cast_weights<<<5 * NLAYER * DD * DD / 256, 256, 0, stream>>>(
      Cw, Aw, Bw, Dw, Ew, Cwb, Anb, Bnb, Dnb, Enb);
  build_ws<<<(DD * SEQ_KP + 255) / 256, 256, 0, stream>>>(emb, conv_w, WSf);

  seq_encoder<<<NN, 256, 0, stream>>>(WSf, conv_b, reads, h, h_bf);
  edge_encoder<<<(EE * DD / 8) / 256, 256, 0, stream>>>(sim, leng, ee_w, ee_b,
                                                        ceid, e);

  for (int i = 0; i < NLAYER; i++) {
    size_t wo = (size_t)i * DD * DD;
    gemm_node_mfma<<<dim3((NN + 127) / 128, 4), 256, 0, stream>>>(
        h_bf, Anb + wo, Bnb + wo, Dnb + wo, Enb + wo,
        Ab + i * DD, Bb + i * DD, Db + i * DD, Eb + i * DD, Ah, Bh, Dh, Eh,
        stats);

    gemm_edge_mfma<<<EE / 128, 256, 0, stream>>>(e, Cwb + wo, Cb + i * DD, Dh,
                                                 Eh, sp, dp, ehat, p1e, p2e);

    agg_fused<<<NN / 4, 256, 0, stream>>>(ehat, e, Bh, Ah, p1e, p2e,
                                          bne_g + i * DD, bne_b + i * DD, coff,
                                          sp, xb, p1n, p2n);

    node_update<<<256, 256, 0, stream>>>(xb, p1n, p2n, bnh_g + i * DD,
                                         bnh_b + i * DD, h, h_bf);
  }

  decoder_k<<<EE / 4, 256, 0, stream>>>(h, e, ceid, sp, dp, dec_w, dec_b, out);
}

// Round 15
// 941.762 us; speedup vs baseline: 1.1677x; 1.1677x over previous
//
#include <hip/hip_runtime.h>
#include <math.h>

#define NN 20000
#define LL 64
#define EE 320000
#define DD 128
#define KK 20
#define NLAYER 4
#define TOUT 45  // LL - KK + 1

#define EPS_BN 1e-5f
#define EPS_AGG 1e-6f

#define SEQ_KP 96   // one-hot K (80) padded to 3 MFMA k-steps
#define SEQ_AP 104  // A-tile row stride (f16): 16B-aligned, 2-way-conflict only

#define ESLOTS 16   // edge-BN stat slots (round-12 win; round-14's 32-slot
                    // per-wave direct atomics doubled WRITE_SIZE -> reverted)

// Wave-local LDS sync: what __syncthreads lowers to for a 1-wave block,
// minus s_barrier. Required between same-wave ds_write -> ds_read.
#define WAVE_LDS_FENCE() __asm__ volatile("s_waitcnt lgkmcnt(0)" ::: "memory")

typedef unsigned short u16;
typedef __attribute__((ext_vector_type(8))) short short8;      // 8 bf16
typedef __attribute__((ext_vector_type(8))) unsigned short ushort8;
typedef __attribute__((ext_vector_type(8))) _Float16 half8;    // 8 f16
typedef __attribute__((ext_vector_type(4))) float floatx4;     // MFMA C/D

// bf16 <-> fp32 (RNE).
__device__ __forceinline__ float b2f(u16 u) {
  union { unsigned int i; float f; } v;
  v.i = ((unsigned int)u) << 16;
  return v.f;
}
__device__ __forceinline__ u16 f2b(float f) {
  union { float f; unsigned int i; } v;
  v.f = f;
  unsigned int x = v.i;
  return (u16)((x + 0x7fffu + ((x >> 16) & 1u)) >> 16);
}

// ---------------------------------------------------------------------------
__global__ void zero_i32(int* __restrict__ p, int n)
{
  int i = blockIdx.x * 256 + threadIdx.x;
  if (i < n) p[i] = 0;
}

__global__ void diag_k(float* __restrict__ out, float v) { out[0] = v; }

// One kernel casts all 5 weight stacks to bf16 (5 * NLAYER*DD*DD elements).
__global__ void cast_weights(
    const float* __restrict__ Cw, const float* __restrict__ Aw,
    const float* __restrict__ Bw, const float* __restrict__ Dw,
    const float* __restrict__ Ew, u16* __restrict__ Cwb, u16* __restrict__ Anb,
    u16* __restrict__ Bnb, u16* __restrict__ Dnb, u16* __restrict__ Enb)
{
  int idx = blockIdx.x * 256 + threadIdx.x;  // exact 5*65536
  int which = idx >> 16, off = idx & 65535;
  const float* s;
  u16* d;
  switch (which) {
    case 0: s = Cw; d = Cwb; break;
    case 1: s = Aw; d = Anb; break;
    case 2: s = Bw; d = Bnb; break;
    case 3: s = Dw; d = Dnb; break;
    default: s = Ew; d = Enb; break;
  }
  d[off] = f2b(s[off]);
}

// ---------------------------------------------------------------------------
// WS[(k,s)][d] = sum_j emb[s][j] * conv_w[d][j][k], fp32 math, stored f16.
// ---------------------------------------------------------------------------
__global__ void build_ws(const float* __restrict__ emb,
                         const float* __restrict__ conv_w,
                         _Float16* __restrict__ WSf)
{
  int idx = blockIdx.x * 256 + threadIdx.x;
  if (idx >= DD * SEQ_KP) return;
  int d = idx / SEQ_KP;
  int c = idx - d * SEQ_KP;
  float v = 0.f;
  if (c < 80) {
    int k = c >> 2, s = c & 3;
    v = emb[s * 3 + 0] * conv_w[d * 60 + k] +
        emb[s * 3 + 1] * conv_w[d * 60 + 20 + k] +
        emb[s * 3 + 2] * conv_w[d * 60 + 40 + k];
  }
  WSf[idx] = (_Float16)v;
}

// ---------------------------------------------------------------------------
// Sequence encoder via f16 MFMA on an EXACT one-hot im2col (round-6 proven).
// ---------------------------------------------------------------------------
__global__ __launch_bounds__(256) void seq_encoder(
    const _Float16* __restrict__ WSf, const float* __restrict__ conv_b,
    const int* __restrict__ reads, float* __restrict__ h,
    u16* __restrict__ h_bf)
{
  __shared__ int rd[LL];
  __shared__ _Float16 As[48][SEQ_AP];
  int tid = threadIdx.x;
  int n = blockIdx.x;
  if (tid < LL) rd[tid] = reads[n * LL + tid];
  __syncthreads();

#pragma unroll
  for (int it = 0; it < 20; it++) {
    int idx = tid + it * 256;  // covers 48*104 = 4992
    if (idx < 48 * SEQ_AP) {
      int t = idx / SEQ_AP;
      int c = idx - t * SEQ_AP;
      _Float16 v = (_Float16)0.f;
      if (t < TOUT && c < 80) {
        int k = c >> 2, s = c & 3;
        v = (rd[t + k] == s) ? (_Float16)1.f : (_Float16)0.f;
      }
      (&As[0][0])[idx] = v;
    }
  }
  __syncthreads();

  int lane = tid & 63;
  int wv = tid >> 6;
  int m = lane & 15;
  int q = lane >> 4;

  half8 a[3][3];
#pragma unroll
  for (int mt = 0; mt < 3; mt++)
#pragma unroll
    for (int ks = 0; ks < 3; ks++)
      a[mt][ks] = *(const half8*)&As[mt * 16 + m][ks * 32 + q * 8];

  floatx4 acc[3][2];
#pragma unroll
  for (int mt = 0; mt < 3; mt++)
#pragma unroll
    for (int nt = 0; nt < 2; nt++) acc[mt][nt] = (floatx4){0.f, 0.f, 0.f, 0.f};

#pragma unroll
  for (int ks = 0; ks < 3; ks++) {
#pragma unroll
    for (int nt = 0; nt < 2; nt++) {
      int row = (wv * 2 + nt) * 16 + m;  // output channel
      half8 b = *(const half8*)(WSf + (size_t)row * SEQ_KP + ks * 32 + q * 8);
#pragma unroll
      for (int mt = 0; mt < 3; mt++)
        acc[mt][nt] = __builtin_amdgcn_mfma_f32_16x16x32_f16(a[mt][ks], b,
                                                             acc[mt][nt], 0, 0, 0);
    }
  }

#pragma unroll
  for (int nt = 0; nt < 2; nt++) {
    float mx = -1e30f;
#pragma unroll
    for (int mt = 0; mt < 3; mt++) {
#pragma unroll
      for (int r = 0; r < 4; r++) {
        int row = mt * 16 + q * 4 + r;
        float v = acc[mt][nt][r];
        mx = (row < TOUT) ? fmaxf(mx, v) : mx;
      }
    }
    mx = fmaxf(mx, __shfl_xor(mx, 16, 64));
    mx = fmaxf(mx, __shfl_xor(mx, 32, 64));
    if (lane < 16) {
      int col = (wv * 2 + nt) * 16 + lane;
      float hv = fmaxf(mx + conv_b[col], 0.f);
      h[n * DD + col] = hv;
      h_bf[n * DD + col] = f2b(hv);
    }
  }
}

// ---------------------------------------------------------------------------
// Edge encoder, CSR-permuted slots, 8 channels (16B store) per thread.
// ---------------------------------------------------------------------------
__global__ __launch_bounds__(256) void edge_encoder(
    const float* __restrict__ sim, const float* __restrict__ len,
    const float* __restrict__ ee_w, const float* __restrict__ ee_b,
    const int* __restrict__ ceid, u16* __restrict__ e)
{
  int idx = blockIdx.x * 256 + threadIdx.x;  // EE*DD/8 exactly
  int p = idx >> 4;
  int c0 = (idx & 15) * 8;
  int eid = ceid[p];
  float sv = sim[eid], lv = len[eid];
  ushort8 o;
#pragma unroll
  for (int j = 0; j < 8; j++) {
    int c = c0 + j;
    o[j] = f2b(fmaf(sv, ee_w[2 * c], fmaf(lv, ee_w[2 * c + 1], ee_b[c])));
  }
  *(ushort8*)&e[(size_t)p * DD + c0] = o;
}

// ---------------------------------------------------------------------------
// CSR build (by dst): histogram -> 1-block scan -> scatter -> permuted arrays
// ---------------------------------------------------------------------------
__global__ void hist_kernel(const int* __restrict__ dst, int* __restrict__ deg)
{
  int i = blockIdx.x * 256 + threadIdx.x;
  if (i < EE) atomicAdd(&deg[dst[i]], 1);
}

__global__ __launch_bounds__(1024) void scan_kernel(
    const int* __restrict__ deg, int* __restrict__ off, int* __restrict__ cur)
{
  __shared__ int ss[1024];
  const int CH = 20;
  int tid = threadIdx.x;
  int base = tid * CH;
  int s = 0;
  for (int j = 0; j < CH; j++) {
    int i = base + j;
    if (i < NN) s += deg[i];
  }
  ss[tid] = s;
  __syncthreads();
  for (int o = 1; o < 1024; o <<= 1) {
    int v = (tid >= o) ? ss[tid - o] : 0;
    __syncthreads();
    ss[tid] += v;
    __syncthreads();
  }
  int run = (tid == 0) ? 0 : ss[tid - 1];
  for (int j = 0; j < CH; j++) {
    int i = base + j;
    if (i < NN) {
      off[i] = run;
      cur[i] = run;
      run += deg[i];
    }
  }
  if (base <= NN && NN < base + CH) off[NN] = run;
}

__global__ void scatter_kernel(const int* __restrict__ dst, int* __restrict__ cur,
                               int* __restrict__ csr)
{
  int i = blockIdx.x * 256 + threadIdx.x;
  if (i < EE) {
    int p = atomicAdd(&cur[dst[i]], 1);
    csr[p] = i;
  }
}

__global__ void build_perm(const int* __restrict__ ceid,
                           const int* __restrict__ src,
                           const int* __restrict__ dst,
                           int* __restrict__ sp, int* __restrict__ dp)
{
  int i = blockIdx.x * 256 + threadIdx.x;
  if (i < EE) {
    int eid = ceid[i];
    sp[i] = src[eid];
    dp[i] = dst[eid];
  }
}

// ---------------------------------------------------------------------------
// Node projections via bf16 MFMA + LDS-transposed coalesced ushort8 stores.
// Gs stride 132 (the +4 skew spreads banks; stride 128 measured 4x the
// conflicts in round 14). Intra-wave syncs are WAVE_LDS_FENCE. Block (0,0)
// zeroes the BN-stats region.
// ---------------------------------------------------------------------------
__global__ __launch_bounds__(256) void gemm_node_mfma(
    const u16* __restrict__ hbf,
    const u16* __restrict__ W0, const u16* __restrict__ W1,
    const u16* __restrict__ W2, const u16* __restrict__ W3,
    const float* __restrict__ b0, const float* __restrict__ b1,
    const float* __restrict__ b2, const float* __restrict__ b3,
    u16* __restrict__ O0, u16* __restrict__ O1,
    u16* __restrict__ O2, u16* __restrict__ O3,
    float* __restrict__ stats)
{
  __shared__ float Gs[4][16][132];
  if (blockIdx.x == 0 && blockIdx.y == 0) {
    const int nstat = 2 * ESLOTS * DD + 2 * 64 * DD;
    for (int j = threadIdx.x; j < nstat; j += 256) stats[j] = 0.f;
  }
  const u16* W;
  const float* bias;
  u16* O;
  switch (blockIdx.y) {
    case 0: W = W0; bias = b0; O = O0; break;
    case 1: W = W1; bias = b1; O = O1; break;
    case 2: W = W2; bias = b2; O = O2; break;
    default: W = W3; bias = b3; O = O3; break;
  }
  int lane = threadIdx.x & 63;
  int wv = threadIdx.x >> 6;
  int rbase = blockIdx.x * 128 + wv * 32;
  int m = lane & 15;
  int q = lane >> 4;

  floatx4 acc[2][8];
#pragma unroll
  for (int rt = 0; rt < 2; rt++)
#pragma unroll
    for (int ct = 0; ct < 8; ct++) acc[rt][ct] = (floatx4){0.f, 0.f, 0.f, 0.f};

  int r0 = rbase + m;
  int r0c = r0 < NN ? r0 : NN - 1;
  int r1c = (r0 + 16) < NN ? (r0 + 16) : NN - 1;
  size_t a0base = (size_t)r0c * DD + q * 8;
  size_t a1base = (size_t)r1c * DD + q * 8;
  size_t bbase = (size_t)m * DD + q * 8;

#pragma unroll
  for (int ks = 0; ks < 4; ks++) {
    short8 a0 = *(const short8*)(hbf + a0base + ks * 32);
    short8 a1 = *(const short8*)(hbf + a1base + ks * 32);
#pragma unroll
    for (int ct = 0; ct < 8; ct++) {
      short8 b = *(const short8*)(W + bbase + (size_t)ct * 16 * DD + ks * 32);
      acc[0][ct] = __builtin_amdgcn_mfma_f32_16x16x32_bf16(a0, b, acc[0][ct], 0, 0, 0);
      acc[1][ct] = __builtin_amdgcn_mfma_f32_16x16x32_bf16(a1, b, acc[1][ct], 0, 0, 0);
    }
  }

  float cb[8];
#pragma unroll
  for (int ct = 0; ct < 8; ct++) cb[ct] = bias[ct * 16 + m];

  int rg = lane >> 4, cg = lane & 15;
#pragma unroll
  for (int rt = 0; rt < 2; rt++) {
#pragma unroll
    for (int ct = 0; ct < 8; ct++)
#pragma unroll
      for (int r = 0; r < 4; r++)
        Gs[wv][q * 4 + r][ct * 16 + m] = acc[rt][ct][r] + cb[ct];
    WAVE_LDS_FENCE();  // writes committed before same-wave reads
#pragma unroll
    for (int k = 0; k < 4; k++) {
      int ri = k * 4 + rg;
      int grow = rbase + rt * 16 + ri;
      if (grow < NN) {
        ushort8 ov;
#pragma unroll
        for (int j = 0; j < 8; j++) ov[j] = f2b(Gs[wv][ri][cg * 8 + j]);
        *(ushort8*)(O + (size_t)grow * DD + cg * 8) = ov;
      }
    }
    WAVE_LDS_FENCE();  // reads done before next rt overwrites the tile
  }
}

// ---------------------------------------------------------------------------
// E1: edge GEMM (bf16 MFMA) + LDS-transposed epilogue + fused BN stats
// (block-reduced into LDS then ESLOTS-spread atomics — round-13 proven).
// ---------------------------------------------------------------------------
__global__ __launch_bounds__(256) void gemm_edge_mfma(
    const u16* __restrict__ e, const u16* __restrict__ Cwb,
    const float* __restrict__ Cb, const u16* __restrict__ Dh,
    const u16* __restrict__ Eh, const int* __restrict__ sp,
    const int* __restrict__ dp, u16* __restrict__ ehat,
    float* __restrict__ p1e, float* __restrict__ p2e)
{
  __shared__ float Gs[4][16][132];
  __shared__ float s1s[4][128], s2s[4][128];
  int lane = threadIdx.x & 63;
  int wv = threadIdx.x >> 6;
  int rbase = blockIdx.x * 128 + wv * 32;
  int m = lane & 15;
  int q = lane >> 4;
  int rg = q, cg = m;
  int c0 = cg * 8;

  // Prefetch epilogue gather indices (independent of the GEMM).
  int dnv[8], snv[8];
#pragma unroll
  for (int rt = 0; rt < 2; rt++)
#pragma unroll
    for (int k = 0; k < 4; k++) {
      int grow = rbase + rt * 16 + k * 4 + rg;
      dnv[rt * 4 + k] = dp[grow];
      snv[rt * 4 + k] = sp[grow];
    }

  floatx4 acc[2][8];
#pragma unroll
  for (int rt = 0; rt < 2; rt++)
#pragma unroll
    for (int ct = 0; ct < 8; ct++) acc[rt][ct] = (floatx4){0.f, 0.f, 0.f, 0.f};

  size_t abase = (size_t)(rbase + m) * DD + q * 8;
  size_t bbase = (size_t)m * DD + q * 8;

#pragma unroll
  for (int ks = 0; ks < 4; ks++) {
    short8 a0 = *(const short8*)(e + abase + ks * 32);
    short8 a1 = *(const short8*)(e + abase + 16 * DD + ks * 32);
#pragma unroll
    for (int ct = 0; ct < 8; ct++) {
      short8 b = *(const short8*)(Cwb + bbase + (size_t)ct * 16 * DD + ks * 32);
      acc[0][ct] = __builtin_amdgcn_mfma_f32_16x16x32_bf16(a0, b, acc[0][ct], 0, 0, 0);
      acc[1][ct] = __builtin_amdgcn_mfma_f32_16x16x32_bf16(a1, b, acc[1][ct], 0, 0, 0);
    }
  }

  float cb[8];
#pragma unroll
  for (int ct = 0; ct < 8; ct++) cb[ct] = Cb[ct * 16 + m];

  float s1[8], s2[8];
#pragma unroll
  for (int j = 0; j < 8; j++) { s1[j] = 0.f; s2[j] = 0.f; }

#pragma unroll
  for (int rt = 0; rt < 2; rt++) {
#pragma unroll
    for (int ct = 0; ct < 8; ct++)
#pragma unroll
      for (int r = 0; r < 4; r++)
        Gs[wv][q * 4 + r][ct * 16 + m] = acc[rt][ct][r] + cb[ct];
    WAVE_LDS_FENCE();
#pragma unroll
    for (int k = 0; k < 4; k++) {
      int ri = k * 4 + rg;
      int grow = rbase + rt * 16 + ri;
      int dn = dnv[rt * 4 + k], sn = snv[rt * 4 + k];
      ushort8 dh = *(const ushort8*)(Dh + (size_t)dn * DD + c0);
      ushort8 eh = *(const ushort8*)(Eh + (size_t)sn * DD + c0);
      ushort8 ov;
#pragma unroll
      for (int j = 0; j < 8; j++) {
        float v = Gs[wv][ri][c0 + j] + b2f(dh[j]) + b2f(eh[j]);
        ov[j] = f2b(v);
        s1[j] += v;
        s2[j] = fmaf(v, v, s2[j]);
      }
      *(ushort8*)(ehat + (size_t)grow * DD + c0) = ov;
    }
    WAVE_LDS_FENCE();
  }

#pragma unroll
  for (int j = 0; j < 8; j++) {
    float a1 = s1[j], a2 = s2[j];
    a1 += __shfl_down(a1, 16, 64);
    a1 += __shfl_down(a1, 32, 64);
    a2 += __shfl_down(a2, 16, 64);
    a2 += __shfl_down(a2, 32, 64);
    if (rg == 0) {
      s1s[wv][c0 + j] = a1;
      s2s[wv][c0 + j] = a2;
    }
  }
  __syncthreads();
  if (threadIdx.x < 128) {
    int c = threadIdx.x;
    int slot = (blockIdx.x & (ESLOTS - 1)) * DD;
    atomicAdd(&p1e[slot + c], s1s[0][c] + s1s[1][c] + s1s[2][c] + s1s[3][c]);
    atomicAdd(&p2e[slot + c], s2s[0][c] + s2s[1][c] + s2s[2][c] + s2s[3][c]);
  }
}

// ---------------------------------------------------------------------------
// E2: fused edge_update + aggregation. Two 32-lane halves per wave process
// different CSR rows (round-13 win). BN-e finalize computed once per block
// into LDS (round-14's one good change).
// ---------------------------------------------------------------------------
__global__ __launch_bounds__(256) void agg_fused(
    const u16* __restrict__ ehat, u16* __restrict__ e,
    const u16* __restrict__ Bh, const u16* __restrict__ Ah,
    const float* __restrict__ p1e, const float* __restrict__ p2e,
    const float* __restrict__ bng, const float* __restrict__ bnb,
    const int* __restrict__ coff, const int* __restrict__ sp,
    float* __restrict__ xb, float* __restrict__ p1n, float* __restrict__ p2n)
{
  __shared__ float xs[4][128];
  __shared__ float scs[128], shs[128];
  int tid = threadIdx.x;
  if (tid < 128) {
    int c = tid;
    float s1 = 0.f, s2 = 0.f;
    for (int k = 0; k < ESLOTS; k++) {
      s1 += p1e[k * DD + c];
      s2 += p2e[k * DD + c];
    }
    const float inv = 1.f / (float)EE;
    float mean = s1 * inv;
    float var = fmaxf(s2 * inv - mean * mean, 0.f);
    float sc = bng[c] * rsqrtf(var + EPS_BN);
    scs[c] = sc;
    shs[c] = fmaf(-mean, sc, bnb[c]);
  }
  __syncthreads();

  int wv = tid >> 6;
  int n = blockIdx.x * 4 + wv;  // NN = 20000 exact
  int lane = tid & 63;
  int half = lane >> 5;
  int sub = lane & 31;
  int c4 = sub * 4;

  float4 scv = *(const float4*)&scs[c4];
  float4 shv = *(const float4*)&shs[c4];
  float sc[4] = {scv.x, scv.y, scv.z, scv.w};
  float sh[4] = {shv.x, shv.y, shv.z, shv.w};

  int b = coff[n], en = coff[n + 1];
  float num[4] = {0.f, 0.f, 0.f, 0.f}, den[4] = {0.f, 0.f, 0.f, 0.f};
  for (int pb = b; pb < en; pb += 2) {
    int p = pb + half;
    if (p < en) {
      int sn = sp[p];
      ushort4 hv = *(const ushort4*)&ehat[(size_t)p * DD + c4];
      ushort4 ev = *(const ushort4*)&e[(size_t)p * DD + c4];
      ushort4 bh = *(const ushort4*)&Bh[(size_t)sn * DD + c4];
      u16 hvv[4] = {hv.x, hv.y, hv.z, hv.w};
      u16 evv[4] = {ev.x, ev.y, ev.z, ev.w};
      u16 bhv[4] = {bh.x, bh.y, bh.z, bh.w};
      u16 eo[4];
#pragma unroll
      for (int j = 0; j < 4; j++) {
        float v = b2f(hvv[j]);
        eo[j] = f2b(b2f(evv[j]) + fmaxf(fmaf(v, sc[j], sh[j]), 0.f));
        float s = 1.f / (1.f + __expf(-v));
        den[j] += s;
        num[j] = fmaf(s, b2f(bhv[j]), num[j]);
      }
      ushort4 eow = {eo[0], eo[1], eo[2], eo[3]};
      *(ushort4*)&e[(size_t)p * DD + c4] = eow;
    }
  }

#pragma unroll
  for (int j = 0; j < 4; j++) {
    num[j] += __shfl_down(num[j], 32, 64);
    den[j] += __shfl_down(den[j], 32, 64);
  }

  if (half == 0) {
    ushort4 av = *(const ushort4*)&Ah[(size_t)n * DD + c4];
    u16 avv[4] = {av.x, av.y, av.z, av.w};
    float x[4];
#pragma unroll
    for (int j = 0; j < 4; j++)
      x[j] = b2f(avv[j]) + num[j] / (den[j] + EPS_AGG);
    *(float4*)&xb[(size_t)n * DD + c4] = make_float4(x[0], x[1], x[2], x[3]);
#pragma unroll
    for (int j = 0; j < 4; j++) xs[wv][c4 + j] = x[j];
  }
  __syncthreads();
  if (threadIdx.x < 128) {
    int c = threadIdx.x;
    float a0 = xs[0][c], a1 = xs[1][c], a2 = xs[2][c], a3 = xs[3][c];
    float s1v = (a0 + a1) + (a2 + a3);
    float s2v = fmaf(a0, a0, fmaf(a1, a1, fmaf(a2, a2, a3 * a3)));
    int slot = blockIdx.x & 63;
    atomicAdd(&p1n[slot * DD + c], s1v);
    atomicAdd(&p2n[slot * DD + c], s2v);
  }
}

// ---------------------------------------------------------------------------
// Node update: scale/shift computed once per block into LDS, then
// float4/ushort4 grid-stride streaming.
// ---------------------------------------------------------------------------
__global__ __launch_bounds__(256) void node_update(
    const float* __restrict__ x, const float* __restrict__ p1n,
    const float* __restrict__ p2n, const float* __restrict__ g,
    const float* __restrict__ b, float* __restrict__ h,
    u16* __restrict__ h_bf)
{
  __shared__ float scs[128], shs[128];
  int tid = threadIdx.x;
  if (tid < 128) {
    int c = tid;
    float s1 = 0.f, s2 = 0.f;
    for (int k = 0; k < 64; k++) {
      s1 += p1n[k * DD + c];
      s2 += p2n[k * DD + c];
    }
    const float inv = 1.f / (float)NN;
    float mean = s1 * inv;
    float var = fmaxf(s2 * inv - mean * mean, 0.f);
    float sc = g[c] * rsqrtf(var + EPS_BN);
    scs[c] = sc;
    shs[c] = fmaf(-mean, sc, b[c]);
  }
  __syncthreads();
  for (int i = blockIdx.x * 256 + tid; i < NN * DD / 4; i += 256 * 256) {
    int base = i * 4;
    int c0 = base & 127;
    float4 xv = *(const float4*)&x[base];
    float4 hv = *(const float4*)&h[base];
    float4 sc = *(const float4*)&scs[c0];
    float4 shv = *(const float4*)&shs[c0];
    float4 ho;
    ho.x = hv.x + fmaxf(fmaf(xv.x, sc.x, shv.x), 0.f);
    ho.y = hv.y + fmaxf(fmaf(xv.y, sc.y, shv.y), 0.f);
    ho.z = hv.z + fmaxf(fmaf(xv.z, sc.z, shv.z), 0.f);
    ho.w = hv.w + fmaxf(fmaf(xv.w, sc.w, shv.w), 0.f);
    *(float4*)&h[base] = ho;
    ushort4 hb = {f2b(ho.x), f2b(ho.y), f2b(ho.z), f2b(ho.w)};
    *(ushort4*)&h_bf[base] = hb;
  }
}

// ---------------------------------------------------------------------------
// Decoder: one wave per CSR position p; scatter-store to out[ceid[p]].
// ---------------------------------------------------------------------------
__global__ __launch_bounds__(256) void decoder_k(
    const float* __restrict__ h, const u16* __restrict__ e,
    const int* __restrict__ ceid, const int* __restrict__ sp,
    const int* __restrict__ dp, const float* __restrict__ dw,
    const float* __restrict__ db, float* __restrict__ out)
{
  int p = (blockIdx.x * 256 + threadIdx.x) >> 6;  // < EE exactly
  int lane = threadIdx.x & 63;
  int s = sp[p], dd = dp[p];
  float acc = 0.f;
#pragma unroll
  for (int half = 0; half < 2; half++) {
    int c = lane + half * 64;
    acc = fmaf(dw[c], h[(size_t)s * DD + c], acc);
    acc = fmaf(dw[DD + c], h[(size_t)dd * DD + c], acc);
    acc = fmaf(dw[2 * DD + c], b2f(e[(size_t)p * DD + c]), acc);
  }
#pragma unroll
  for (int o = 32; o > 0; o >>= 1) acc += __shfl_down(acc, o, 64);
  if (lane == 0) out[ceid[p]] = acc + db[0];
}

// ---------------------------------------------------------------------------
extern "C" void kernel_launch(void* const* d_in, const int* in_sizes, int n_in,
                              void* d_out, int out_size, void* d_ws, size_t ws_size,
                              hipStream_t stream)
{
  const float* emb = (const float*)d_in[0];
  const float* conv_w = (const float*)d_in[1];
  const float* conv_b = (const float*)d_in[2];
  const float* ee_w = (const float*)d_in[3];
  const float* ee_b = (const float*)d_in[4];
  const float* Aw = (const float*)d_in[5];
  const float* Ab = (const float*)d_in[6];
  const float* Bw = (const float*)d_in[7];
  const float* Bb = (const float*)d_in[8];
  const float* Cw = (const float*)d_in[9];
  const float* Cb = (const float*)d_in[10];
  const float* Dw = (const float*)d_in[11];
  const float* Db = (const float*)d_in[12];
  const float* Ew = (const float*)d_in[13];
  const float* Eb = (const float*)d_in[14];
  const float* bnh_g = (const float*)d_in[15];
  const float* bnh_b = (const float*)d_in[16];
  const float* bne_g = (const float*)d_in[17];
  const float* bne_b = (const float*)d_in[18];
  const float* dec_w = (const float*)d_in[19];
  const float* dec_b = (const float*)d_in[20];
  const float* sim = (const float*)d_in[21];
  const float* leng = (const float*)d_in[22];
  const int* reads = (const int*)d_in[23];
  const int* src = (const int*)d_in[24];
  const int* dst = (const int*)d_in[25];
  float* out = (float*)d_out;

  char* ws = (char*)d_ws;
  size_t off = 0;
  auto alloc = [&](size_t b) -> void* {
    void* p = ws + off;
    off += (b + 255) & ~(size_t)255;
    return p;
  };
  float* h = (float*)alloc((size_t)NN * DD * 4);
  u16* h_bf = (u16*)alloc((size_t)NN * DD * 2);
  u16* e = (u16*)alloc((size_t)EE * DD * 2);       // CSR-permuted
  u16* ehat = (u16*)alloc((size_t)EE * DD * 2);    // CSR-permuted, raw e_hat
  u16* Ah = (u16*)alloc((size_t)NN * DD * 2);
  u16* Bh = (u16*)alloc((size_t)NN * DD * 2);
  u16* Dh = (u16*)alloc((size_t)NN * DD * 2);
  u16* Eh = (u16*)alloc((size_t)NN * DD * 2);
  float* xb = (float*)alloc((size_t)NN * DD * 4);
  float* stats = (float*)alloc((size_t)(2 * ESLOTS * DD + 2 * 64 * DD) * 4);
  float* p1e = stats;
  float* p2e = stats + ESLOTS * DD;
  float* p1n = stats + 2 * ESLOTS * DD;
  float* p2n = p1n + 64 * DD;
  u16* Cwb = (u16*)alloc((size_t)NLAYER * DD * DD * 2);
  u16* Anb = (u16*)alloc((size_t)NLAYER * DD * DD * 2);
  u16* Bnb = (u16*)alloc((size_t)NLAYER * DD * DD * 2);
  u16* Dnb = (u16*)alloc((size_t)NLAYER * DD * DD * 2);
  u16* Enb = (u16*)alloc((size_t)NLAYER * DD * DD * 2);
  _Float16* WSf = (_Float16*)alloc((size_t)DD * SEQ_KP * 2);
  int* deg = (int*)alloc((size_t)NN * 4);
  int* coff = (int*)alloc((size_t)(NN + 1) * 4);
  int* ccur = (int*)alloc((size_t)NN * 4);
  int* ceid = (int*)alloc((size_t)EE * 4);
  int* sp = (int*)alloc((size_t)EE * 4);
  int* dp = (int*)alloc((size_t)EE * 4);

  if (off > ws_size) {
    diag_k<<<1, 1, 0, stream>>>(out, (float)ws_size);
    return;
  }

  // CSR by dst + permuted index arrays (ws re-poisoned every call).
  zero_i32<<<(NN + 255) / 256, 256, 0, stream>>>(deg, NN);
  hist_kernel<<<(EE + 255) / 256, 256, 0, stream>>>(dst, deg);
  scan_kernel<<<1, 1024, 0, stream>>>(deg, coff, ccur);
  scatter_kernel<<<(EE + 255) / 256, 256, 0, stream>>>(dst, ccur, ceid);
  build_perm<<<(EE + 255) / 256, 256, 0, stream>>>(ceid, src, dst, sp, dp);

  cast_weights<<<5 * NLAYER * DD * DD / 256, 256, 0, stream>>>(
      Cw, Aw, Bw, Dw, Ew, Cwb, Anb, Bnb, Dnb, Enb);
  build_ws<<<(DD * SEQ_KP + 255) / 256, 256, 0, stream>>>(emb, conv_w, WSf);

  seq_encoder<<<NN, 256, 0, stream>>>(WSf, conv_b, reads, h, h_bf);
  edge_encoder<<<(EE * DD / 8) / 256, 256, 0, stream>>>(sim, leng, ee_w, ee_b,
                                                        ceid, e);

  for (int i = 0; i < NLAYER; i++) {
    size_t wo = (size_t)i * DD * DD;
    gemm_node_mfma<<<dim3((NN + 127) / 128, 4), 256, 0, stream>>>(
        h_bf, Anb + wo, Bnb + wo, Dnb + wo, Enb + wo,
        Ab + i * DD, Bb + i * DD, Db + i * DD, Eb + i * DD, Ah, Bh, Dh, Eh,
        stats);

    gemm_edge_mfma<<<EE / 128, 256, 0, stream>>>(e, Cwb + wo, Cb + i * DD, Dh,
                                                 Eh, sp, dp, ehat, p1e, p2e);

    agg_fused<<<NN / 4, 256, 0, stream>>>(ehat, e, Bh, Ah, p1e, p2e,
                                          bne_g + i * DD, bne_b + i * DD, coff,
                                          sp, xb, p1n, p2n);

    node_update<<<256, 256, 0, stream>>>(xb, p1n, p2n, bnh_g + i * DD,
                                         bnh_b + i * DD, h, h_bf);
  }

  decoder_k<<<EE / 4, 256, 0, stream>>>(h, e, ceid, sp, dp, dec_w, dec_b, out);
}